// Round 1
// baseline (1212.493 us; speedup 1.0000x reference)
//
#include <hip/hip_runtime.h>
#include <math.h>

// NormalConsistencyLoss: B=4, N=8192, D=3, K=16, fp32 in/out (scalar out).
// Pipeline: [knn_normal_kernel] exact 16-NN + PCA normal via faithful LAPACK
// ssyevd(fp32) port (sign-faithful) -> ws; [loss_kernel] 1 - mean(dot).

#define NPTS 8192
#define NB   4
#define TS   2048

// ---------------- LAPACK single-precision ports (sign-faithful) ----------------

__device__ __forceinline__ float slapy2f(float x, float y){
#pragma clang fp contract(off)
  float xa = fabsf(x), ya = fabsf(y);
  float w = fmaxf(xa, ya), z = fminf(xa, ya);
  if (z == 0.f) return w;
  float t = z / w;
  return w * sqrtf(1.f + t*t);
}

// LAPACK >= 3.10 slartg (new convention: c >= 0 always, r = sign(d,f))
__device__ __forceinline__ void slartgf(float f, float g, float& c, float& s, float& r){
#pragma clang fp contract(off)
  const float safmin = 1.17549435e-38f;
  const float safmax = 8.50705917e37f;
  const float rtmin  = 1.08420217e-19f;   // sqrt(safmin)
  const float rtmax  = 6.52318604e18f;    // sqrt(safmax/2)
  if (g == 0.f){ c = 1.f; s = 0.f; r = f; }
  else if (f == 0.f){ c = 0.f; s = copysignf(1.f, g); r = fabsf(g); }
  else {
    float f1 = fabsf(f), g1 = fabsf(g);
    if (f1 > rtmin && f1 < rtmax && g1 > rtmin && g1 < rtmax){
      float d = sqrtf(f*f + g*g);
      c = f1 / d;
      r = copysignf(d, f);
      s = g / r;
    } else {
      float u = fminf(safmax, fmaxf(safmin, fmaxf(f1, g1)));
      float fs = f/u, gs = g/u;
      float d = sqrtf(fs*fs + gs*gs);
      c = fabsf(fs)/d;
      r = copysignf(d, f);
      r = r*u;
      s = g/r;
    }
  }
}

__device__ __forceinline__ void slaev2f(float a, float b, float cc,
                                        float& rt1, float& rt2, float& cs1, float& sn1){
#pragma clang fp contract(off)
  float sm  = a + cc;
  float df  = a - cc;
  float adf = fabsf(df);
  float tb  = b + b;
  float ab  = fabsf(tb);
  float acmx, acmn;
  if (fabsf(a) > fabsf(cc)){ acmx = a; acmn = cc; } else { acmx = cc; acmn = a; }
  float rt;
  if (adf > ab){ float t = ab/adf; rt = adf*sqrtf(1.f + t*t); }
  else if (adf < ab){ float t = adf/ab; rt = ab*sqrtf(1.f + t*t); }
  else rt = ab*sqrtf(2.f);
  int sgn1;
  if (sm < 0.f){ rt1 = 0.5f*(sm - rt); sgn1 = -1; rt2 = (acmx/rt1)*acmn - (b/rt1)*b; }
  else if (sm > 0.f){ rt1 = 0.5f*(sm + rt); sgn1 = 1; rt2 = (acmx/rt1)*acmn - (b/rt1)*b; }
  else { rt1 = 0.5f*rt; rt2 = -0.5f*rt; sgn1 = 1; }
  int sgn2; float cs;
  if (df >= 0.f){ cs = df + rt; sgn2 = 1; } else { cs = df - rt; sgn2 = -1; }
  float acs = fabsf(cs);
  if (acs > ab){ float ct = -tb/cs; sn1 = 1.f/sqrtf(1.f + ct*ct); cs1 = ct*sn1; }
  else {
    if (ab == 0.f){ cs1 = 1.f; sn1 = 0.f; }
    else { float tn = -cs/tb; cs1 = 1.f/sqrtf(1.f + tn*tn); sn1 = tn*cs1; }
  }
  if (sgn1 == sgn2){ float tn = cs1; cs1 = -sn1; sn1 = tn; }
}

// dlasr 'R','V' single rotation on columns (ja, ja+1) of 3x3 Z
__device__ __forceinline__ void rot2(float z[3][3], int ja, float c, float s){
#pragma clang fp contract(off)
  #pragma unroll
  for (int i = 0; i < 3; ++i){
    float t1 = z[i][ja+1];
    float t0 = z[i][ja];
    z[i][ja+1] = c*t1 - s*t0;
    z[i][ja]   = s*t1 + c*t0;
  }
}

// Faithful port of LAPACK ssteqr('I', n=3, d, e, z)
__device__ __noinline__ void ssteqr3(float* d, float* e, float z[3][3]){
#pragma clang fp contract(off)
  const float eps    = 5.96046448e-08f;  // slamch('E') = 2^-24
  const float eps2   = 3.55271368e-15f;  // eps^2
  const float safmin = 1.17549435e-38f;
  const float ssfmax = 3.07445735e+18f;  // sqrt(1/safmin)/3
  const float ssfmin = 3.05175781e-05f;  // sqrt(safmin)/eps^2 = 2^-15
  const int n = 3;
  float cw[2], sw[2];
  int nmaxit, jtot, l1, l, lsv, lend, lendsv, m, iscale, i, j, ii, k;
  float anorm, p, g, r, c, s, f, b, rt1, rt2, tst, mul;

  for (i = 0; i < 3; ++i) for (j = 0; j < 3; ++j) z[i][j] = (i == j) ? 1.f : 0.f;
  nmaxit = n*30; jtot = 0; l1 = 1; m = 0; iscale = 0; anorm = 0.f;
  lsv = 1; lendsv = 1; lend = 1; l = 1;

L10:
  if (l1 > n) goto L160;
  if (l1 > 1) e[l1-2] = 0.f;
  if (l1 <= n-1){
    for (m = l1; m <= n-1; ++m){
      tst = fabsf(e[m-1]);
      if (tst == 0.f) goto L30;
      if (tst <= (sqrtf(fabsf(d[m-1]))*sqrtf(fabsf(d[m])))*eps){ e[m-1] = 0.f; goto L30; }
    }
  }
  m = n;
L30:
  l = l1; lsv = l; lend = m; lendsv = lend; l1 = m + 1;
  if (lend == l) goto L10;
  anorm = 0.f;
  for (i = l; i <= lend; ++i)   anorm = fmaxf(anorm, fabsf(d[i-1]));
  for (i = l; i <= lend-1; ++i) anorm = fmaxf(anorm, fabsf(e[i-1]));
  iscale = 0;
  if (anorm == 0.f) goto L10;
  if (anorm > ssfmax){
    iscale = 1; mul = ssfmax/anorm;
    for (i = l; i <= lend; ++i)   d[i-1] *= mul;
    for (i = l; i <= lend-1; ++i) e[i-1] *= mul;
  } else if (anorm < ssfmin){
    iscale = 2; mul = ssfmin/anorm;
    for (i = l; i <= lend; ++i)   d[i-1] *= mul;
    for (i = l; i <= lend-1; ++i) e[i-1] *= mul;
  }
  if (fabsf(d[lend-1]) < fabsf(d[l-1])){ lend = lsv; l = lendsv; }

  if (lend > l){
    /* ---- QL iteration ---- */
L40:
    if (l != lend){
      for (m = l; m <= lend-1; ++m){
        tst = fabsf(e[m-1]); tst = tst*tst;
        if (tst <= (eps2*fabsf(d[m-1]))*fabsf(d[m]) + safmin) goto L60;
      }
    }
    m = lend;
L60:
    if (m < lend) e[m-1] = 0.f;
    p = d[l-1];
    if (m == l) goto L80;
    if (m == l+1){
      slaev2f(d[l-1], e[l-1], d[l], rt1, rt2, c, s);
      rot2(z, l-1, c, s);
      d[l-1] = rt1; d[l] = rt2; e[l-1] = 0.f;
      l += 2;
      if (l <= lend) goto L40;
      goto L140;
    }
    if (jtot == nmaxit) goto L140;
    jtot++;
    g = (d[l] - p)/(2.f*e[l-1]);
    r = slapy2f(g, 1.f);
    g = d[m-1] - p + (e[l-1]/(g + copysignf(r, g)));
    s = 1.f; c = 1.f; p = 0.f;
    for (i = m-1; i >= l; --i){
      f = s*e[i-1];
      b = c*e[i-1];
      slartgf(g, f, c, s, r);
      if (i != m-1) e[i] = r;
      g = d[i] - p;
      r = (d[i-1] - g)*s + 2.f*c*b;
      p = s*r;
      d[i] = g + p;
      g = c*r - b;
      cw[i-l] = c; sw[i-l] = -s;     // work(i)=c, work(n-1+i)=-s
    }
    for (j = m-l; j >= 1; --j) rot2(z, l+j-2, cw[j-1], sw[j-1]);  // 'B' order
    d[l-1] = d[l-1] - p;
    e[l-1] = g;
    goto L40;
L80:
    d[l-1] = p;
    l += 1;
    if (l <= lend) goto L40;
    goto L140;
  } else {
    /* ---- QR iteration ---- */
L90:
    if (l != lend){
      for (m = l; m >= lend+1; --m){
        tst = fabsf(e[m-2]); tst = tst*tst;
        if (tst <= (eps2*fabsf(d[m-1]))*fabsf(d[m-2]) + safmin) goto L110;
      }
    }
    m = lend;
L110:
    if (m > lend) e[m-2] = 0.f;
    p = d[l-1];
    if (m == l) goto L130;
    if (m == l-1){
      slaev2f(d[l-2], e[l-2], d[l-1], rt1, rt2, c, s);
      rot2(z, l-2, c, s);
      d[l-2] = rt1; d[l-1] = rt2; e[l-2] = 0.f;
      l -= 2;
      if (l >= lend) goto L90;
      goto L140;
    }
    if (jtot == nmaxit) goto L140;
    jtot++;
    g = (d[l-2] - p)/(2.f*e[l-2]);
    r = slapy2f(g, 1.f);
    g = d[m-1] - p + (e[l-2]/(g + copysignf(r, g)));
    s = 1.f; c = 1.f; p = 0.f;
    for (i = m; i <= l-1; ++i){
      f = s*e[i-1];
      b = c*e[i-1];
      slartgf(g, f, c, s, r);
      if (i != m) e[i-2] = r;
      g = d[i-1] - p;
      r = (d[i] - g)*s + 2.f*c*b;
      p = s*r;
      d[i-1] = g + p;
      g = c*r - b;
      cw[i-m] = c; sw[i-m] = s;      // work(i)=c, work(n-1+i)=s
    }
    for (j = 1; j <= l-m; ++j) rot2(z, m+j-2, cw[j-1], sw[j-1]);  // 'F' order
    d[l-1] = d[l-1] - p;
    e[l-2] = g;
    goto L90;
L130:
    d[l-1] = p;
    l -= 1;
    if (l >= lend) goto L90;
    goto L140;
  }
L140:
  if (iscale == 1){
    mul = anorm/ssfmax;
    for (i = lsv; i <= lendsv; ++i)   d[i-1] *= mul;
    for (i = lsv; i <= lendsv-1; ++i) e[i-1] *= mul;
  } else if (iscale == 2){
    mul = anorm/ssfmin;
    for (i = lsv; i <= lendsv; ++i)   d[i-1] *= mul;
    for (i = lsv; i <= lendsv-1; ++i) e[i-1] *= mul;
  }
  if (jtot < nmaxit) goto L10;
  return;
L160:
  /* selection sort ascending; swap eigenvector columns */
  for (ii = 2; ii <= n; ++ii){
    i = ii - 1; k = i; p = d[i-1];
    for (j = ii; j <= n; ++j){
      if (d[j-1] < p){ k = j; p = d[j-1]; }
    }
    if (k != i){
      d[k-1] = d[i-1]; d[i-1] = p;
      for (j = 0; j < 3; ++j){ float t = z[j][i-1]; z[j][i-1] = z[j][k-1]; z[j][k-1] = t; }
    }
  }
}

// ssyevd('V','L') for 3x3: ssytd2 -> ssteqr -> sormtr; returns eigvec of
// smallest eigenvalue (column 0 after ascending sort).
__device__ __noinline__ void eigh3_normal(float a11, float a21, float a31,
                                          float a22, float a32, float a33,
                                          float* out3){
#pragma clang fp contract(off)
  float d[3], e[2], z[3][3];
  float tau1 = 0.f, v2 = 0.f;
  float alpha = a21;
  float xnorm = fabsf(a31);
  if (xnorm == 0.f){
    e[0] = alpha;
    tau1 = 0.f;
  } else {
    float beta = -copysignf(slapy2f(alpha, xnorm), alpha);  // slarfg
    tau1 = (beta - alpha)/beta;
    v2 = a31*(1.f/(alpha - beta));
    // ssymv (lower, exact reference op order)
    float x1 = tau1*a22 + tau1*(a32*v2);
    float x2 = tau1*a32 + (tau1*v2)*a33;
    float al = -0.5f*tau1*(x1 + x2*v2);                      // -half*tau*sdot
    float w1 = x1 + al;                                      // saxpy
    float w2 = x2 + al*v2;
    // ssyr2 alpha=-1
    a22 = a22 - w1 - w1;
    a32 = a32 - v2*w1 - w2;
    a33 = a33 - v2*w2 - w2*v2;
    e[0] = beta;
  }
  e[1] = a32;
  d[0] = a11; d[1] = a22; d[2] = a33;
  ssteqr3(d, e, z);
  // sormtr: apply H1 = I - tau * v v^T (v = (0,1,v2)) from the left
  if (tau1 != 0.f){
    #pragma unroll
    for (int jj = 0; jj < 3; ++jj){
      float wj  = z[1][jj] + v2*z[2][jj];
      float tmp = tau1*wj;
      z[1][jj] = z[1][jj] - tmp;
      z[2][jj] = z[2][jj] - v2*tmp;
    }
  }
  out3[0] = z[0][0]; out3[1] = z[1][0]; out3[2] = z[2][0];
}

// ---------------- distance helpers (contract off => exact self-zero) ----------------

__device__ __forceinline__ float sq3f(float x, float y, float z){
#pragma clang fp contract(off)
  return x*x + y*y + z*z;
}

__device__ __forceinline__ float d2f(float qs, float qx, float qy, float qz, float4 c){
#pragma clang fp contract(off)
  float dot = qx*c.x + qy*c.y + qz*c.z;
  return (qs + c.w) - 2.f*dot;
}

// ---------------- kernels ----------------

// grid 256 blocks x 256 thr: blocks [0,128) = pred, [128,256) = gt.
// Each thread: one query point; brute-force stable 16-NN; PCA normal.
__global__ __launch_bounds__(256) void knn_normal_kernel(const float* __restrict__ pred,
                                                         const float* __restrict__ gt,
                                                         float* __restrict__ normals){
#pragma clang fp contract(off)
  __shared__ float4 tile[TS];
  const int cloud = blockIdx.x >> 7;
  const int wi    = blockIdx.x & 127;
  const int b     = wi >> 5;          // batch 0..3
  const int chunk = wi & 31;          // 0..31
  const float* __restrict__ base = (cloud ? gt : pred) + (size_t)b*(NPTS*3);
  const int qi = chunk*256 + threadIdx.x;
  const float qx = base[qi*3+0];
  const float qy = base[qi*3+1];
  const float qz = base[qi*3+2];
  const float qs = sq3f(qx, qy, qz);

  float bd[16]; int bidx[16];
  #pragma unroll
  for (int j = 0; j < 16; ++j){ bd[j] = 3.0e38f; bidx[j] = 0; }

  for (int t0 = 0; t0 < NPTS; t0 += TS){
    __syncthreads();
    for (int t = threadIdx.x; t < TS; t += 256){
      const float* p = base + (size_t)(t0+t)*3;
      float x = p[0], y = p[1], z = p[2];
      tile[t] = make_float4(x, y, z, sq3f(x, y, z));
    }
    __syncthreads();
    #pragma unroll 4
    for (int t = 0; t < TS; ++t){
      float4 cpt = tile[t];                    // wave-uniform broadcast read
      float dd = d2f(qs, qx, qy, qz, cpt);
      if (dd < bd[15]){                        // strict <: stable tie-break (lower idx wins)
        bd[15] = dd; bidx[15] = t0 + t;
        #pragma unroll
        for (int j = 15; j > 0; --j){
          if (bd[j] < bd[j-1]){
            float td = bd[j]; bd[j] = bd[j-1]; bd[j-1] = td;
            int ti = bidx[j]; bidx[j] = bidx[j-1]; bidx[j-1] = ti;
          }
        }
      }
    }
  }

  // gather neighbors in top_k order (ascending d2, ties by index)
  float gxx[16], gyy[16], gzz[16];
  #pragma unroll
  for (int r = 0; r < 16; ++r){
    const float* p = base + (size_t)bidx[r]*3;
    gxx[r] = p[0]; gyy[r] = p[1]; gzz[r] = p[2];
  }
  float mx = 0.f, my = 0.f, mz = 0.f;
  #pragma unroll
  for (int r = 0; r < 16; ++r){ mx += gxx[r]; my += gyy[r]; mz += gzz[r]; }
  mx *= 0.0625f; my *= 0.0625f; mz *= 0.0625f;

  float c00=0.f, c10=0.f, c20=0.f, c11=0.f, c21=0.f, c22=0.f;
  #pragma unroll
  for (int r = 0; r < 16; ++r){
    float cx = gxx[r]-mx, cy = gyy[r]-my, cz = gzz[r]-mz;
    c00 += cx*cx; c10 += cy*cx; c20 += cz*cx;
    c11 += cy*cy; c21 += cz*cy; c22 += cz*cz;
  }
  c00 *= 0.0625f; c10 *= 0.0625f; c20 *= 0.0625f;
  c11 *= 0.0625f; c21 *= 0.0625f; c22 *= 0.0625f;

  float nrm[3];
  eigh3_normal(c00, c10, c20, c11, c21, c22, nrm);

  float* o = normals + ((size_t)(cloud*NB + b)*NPTS + qi)*3;
  o[0] = nrm[0]; o[1] = nrm[1]; o[2] = nrm[2];
}

__global__ __launch_bounds__(1024) void loss_kernel(const float* __restrict__ normals,
                                                    float* __restrict__ out){
#pragma clang fp contract(off)
  __shared__ float red[1024];
  const int BN = NB*NPTS;
  float acc = 0.f;
  for (int p = threadIdx.x; p < BN; p += 1024){
    const float* a = normals + (size_t)p*3;
    const float* g = normals + (size_t)(BN + p)*3;
    acc += a[0]*g[0] + a[1]*g[1] + a[2]*g[2];
  }
  red[threadIdx.x] = acc;
  __syncthreads();
  for (int sft = 512; sft > 0; sft >>= 1){
    if (threadIdx.x < sft) red[threadIdx.x] += red[threadIdx.x + sft];
    __syncthreads();
  }
  if (threadIdx.x == 0) out[0] = 1.f - red[0]*(1.f/32768.f);
}

extern "C" void kernel_launch(void* const* d_in, const int* in_sizes, int n_in,
                              void* d_out, int out_size, void* d_ws, size_t ws_size,
                              hipStream_t stream) {
  const float* pred = (const float*)d_in[0];
  const float* gt   = (const float*)d_in[1];
  float* normals = (float*)d_ws;      // 2 * 4 * 8192 * 3 floats = 786 KiB
  knn_normal_kernel<<<256, 256, 0, stream>>>(pred, gt, normals);
  loss_kernel<<<1, 1024, 0, stream>>>(normals, (float*)d_out);
}

// Round 3
// 938.497 us; speedup vs baseline: 1.2920x; 1.2920x over previous
//
#include <hip/hip_runtime.h>
#include <math.h>

// NormalConsistencyLoss: B=4, N=8192, D=3, K=16, fp32 in/out (scalar out).
// [knn_normal_kernel] exact 16-NN (4-way split scan + exact lex merge) + PCA
// normal via faithful LAPACK ssyevd(fp32) port -> ws; [loss_kernel] 1-mean(dot).

#define NPTS 8192
#define NB   4
#define TS   2048

// ---------------- LAPACK single-precision ports (sign-faithful) ----------------

__device__ __forceinline__ float slapy2f(float x, float y){
#pragma clang fp contract(off)
  float xa = fabsf(x), ya = fabsf(y);
  float w = fmaxf(xa, ya), z = fminf(xa, ya);
  if (z == 0.f) return w;
  float t = z / w;
  return w * sqrtf(1.f + t*t);
}

// LAPACK >= 3.10 slartg (new convention: c >= 0 always, r = sign(d,f))
__device__ __forceinline__ void slartgf(float f, float g, float& c, float& s, float& r){
#pragma clang fp contract(off)
  const float safmin = 1.17549435e-38f;
  const float safmax = 8.50705917e37f;
  const float rtmin  = 1.08420217e-19f;
  const float rtmax  = 6.52318604e18f;
  if (g == 0.f){ c = 1.f; s = 0.f; r = f; }
  else if (f == 0.f){ c = 0.f; s = copysignf(1.f, g); r = fabsf(g); }
  else {
    float f1 = fabsf(f), g1 = fabsf(g);
    if (f1 > rtmin && f1 < rtmax && g1 > rtmin && g1 < rtmax){
      float d = sqrtf(f*f + g*g);
      c = f1 / d;
      r = copysignf(d, f);
      s = g / r;
    } else {
      float u = fminf(safmax, fmaxf(safmin, fmaxf(f1, g1)));
      float fs = f/u, gs = g/u;
      float d = sqrtf(fs*fs + gs*gs);
      c = fabsf(fs)/d;
      r = copysignf(d, f);
      r = r*u;
      s = g/r;
    }
  }
}

__device__ __forceinline__ void slaev2f(float a, float b, float cc,
                                        float& rt1, float& rt2, float& cs1, float& sn1){
#pragma clang fp contract(off)
  float sm  = a + cc;
  float df  = a - cc;
  float adf = fabsf(df);
  float tb  = b + b;
  float ab  = fabsf(tb);
  float acmx, acmn;
  if (fabsf(a) > fabsf(cc)){ acmx = a; acmn = cc; } else { acmx = cc; acmn = a; }
  float rt;
  if (adf > ab){ float t = ab/adf; rt = adf*sqrtf(1.f + t*t); }
  else if (adf < ab){ float t = adf/ab; rt = ab*sqrtf(1.f + t*t); }
  else rt = ab*sqrtf(2.f);
  int sgn1;
  if (sm < 0.f){ rt1 = 0.5f*(sm - rt); sgn1 = -1; rt2 = (acmx/rt1)*acmn - (b/rt1)*b; }
  else if (sm > 0.f){ rt1 = 0.5f*(sm + rt); sgn1 = 1; rt2 = (acmx/rt1)*acmn - (b/rt1)*b; }
  else { rt1 = 0.5f*rt; rt2 = -0.5f*rt; sgn1 = 1; }
  int sgn2; float cs;
  if (df >= 0.f){ cs = df + rt; sgn2 = 1; } else { cs = df - rt; sgn2 = -1; }
  float acs = fabsf(cs);
  if (acs > ab){ float ct = -tb/cs; sn1 = 1.f/sqrtf(1.f + ct*ct); cs1 = ct*sn1; }
  else {
    if (ab == 0.f){ cs1 = 1.f; sn1 = 0.f; }
    else { float tn = -cs/tb; cs1 = 1.f/sqrtf(1.f + tn*tn); sn1 = tn*cs1; }
  }
  if (sgn1 == sgn2){ float tn = cs1; cs1 = -sn1; sn1 = tn; }
}

__device__ __forceinline__ void rot2(float z[3][3], int ja, float c, float s){
#pragma clang fp contract(off)
  #pragma unroll
  for (int i = 0; i < 3; ++i){
    float t1 = z[i][ja+1];
    float t0 = z[i][ja];
    z[i][ja+1] = c*t1 - s*t0;
    z[i][ja]   = s*t1 + c*t0;
  }
}

// Faithful port of LAPACK ssteqr('I', n=3, d, e, z)
__device__ __noinline__ void ssteqr3(float* d, float* e, float z[3][3]){
#pragma clang fp contract(off)
  const float eps    = 5.96046448e-08f;
  const float eps2   = 3.55271368e-15f;
  const float safmin = 1.17549435e-38f;
  const float ssfmax = 3.07445735e+18f;
  const float ssfmin = 3.05175781e-05f;
  const int n = 3;
  float cw[2], sw[2];
  int nmaxit, jtot, l1, l, lsv, lend, lendsv, m, iscale, i, j, ii, k;
  float anorm, p, g, r, c, s, f, b, rt1, rt2, tst, mul;

  for (i = 0; i < 3; ++i) for (j = 0; j < 3; ++j) z[i][j] = (i == j) ? 1.f : 0.f;
  nmaxit = n*30; jtot = 0; l1 = 1; m = 0; iscale = 0; anorm = 0.f;
  lsv = 1; lendsv = 1; lend = 1; l = 1;

L10:
  if (l1 > n) goto L160;
  if (l1 > 1) e[l1-2] = 0.f;
  if (l1 <= n-1){
    for (m = l1; m <= n-1; ++m){
      tst = fabsf(e[m-1]);
      if (tst == 0.f) goto L30;
      if (tst <= (sqrtf(fabsf(d[m-1]))*sqrtf(fabsf(d[m])))*eps){ e[m-1] = 0.f; goto L30; }
    }
  }
  m = n;
L30:
  l = l1; lsv = l; lend = m; lendsv = lend; l1 = m + 1;
  if (lend == l) goto L10;
  anorm = 0.f;
  for (i = l; i <= lend; ++i)   anorm = fmaxf(anorm, fabsf(d[i-1]));
  for (i = l; i <= lend-1; ++i) anorm = fmaxf(anorm, fabsf(e[i-1]));
  iscale = 0;
  if (anorm == 0.f) goto L10;
  if (anorm > ssfmax){
    iscale = 1; mul = ssfmax/anorm;
    for (i = l; i <= lend; ++i)   d[i-1] *= mul;
    for (i = l; i <= lend-1; ++i) e[i-1] *= mul;
  } else if (anorm < ssfmin){
    iscale = 2; mul = ssfmin/anorm;
    for (i = l; i <= lend; ++i)   d[i-1] *= mul;
    for (i = l; i <= lend-1; ++i) e[i-1] *= mul;
  }
  if (fabsf(d[lend-1]) < fabsf(d[l-1])){ lend = lsv; l = lendsv; }

  if (lend > l){
L40:
    if (l != lend){
      for (m = l; m <= lend-1; ++m){
        tst = fabsf(e[m-1]); tst = tst*tst;
        if (tst <= (eps2*fabsf(d[m-1]))*fabsf(d[m]) + safmin) goto L60;
      }
    }
    m = lend;
L60:
    if (m < lend) e[m-1] = 0.f;
    p = d[l-1];
    if (m == l) goto L80;
    if (m == l+1){
      slaev2f(d[l-1], e[l-1], d[l], rt1, rt2, c, s);
      rot2(z, l-1, c, s);
      d[l-1] = rt1; d[l] = rt2; e[l-1] = 0.f;
      l += 2;
      if (l <= lend) goto L40;
      goto L140;
    }
    if (jtot == nmaxit) goto L140;
    jtot++;
    g = (d[l] - p)/(2.f*e[l-1]);
    r = slapy2f(g, 1.f);
    g = d[m-1] - p + (e[l-1]/(g + copysignf(r, g)));
    s = 1.f; c = 1.f; p = 0.f;
    for (i = m-1; i >= l; --i){
      f = s*e[i-1];
      b = c*e[i-1];
      slartgf(g, f, c, s, r);
      if (i != m-1) e[i] = r;
      g = d[i] - p;
      r = (d[i-1] - g)*s + 2.f*c*b;
      p = s*r;
      d[i] = g + p;
      g = c*r - b;
      cw[i-l] = c; sw[i-l] = -s;
    }
    for (j = m-l; j >= 1; --j) rot2(z, l+j-2, cw[j-1], sw[j-1]);
    d[l-1] = d[l-1] - p;
    e[l-1] = g;
    goto L40;
L80:
    d[l-1] = p;
    l += 1;
    if (l <= lend) goto L40;
    goto L140;
  } else {
L90:
    if (l != lend){
      for (m = l; m >= lend+1; --m){
        tst = fabsf(e[m-2]); tst = tst*tst;
        if (tst <= (eps2*fabsf(d[m-1]))*fabsf(d[m-2]) + safmin) goto L110;
      }
    }
    m = lend;
L110:
    if (m > lend) e[m-2] = 0.f;
    p = d[l-1];
    if (m == l) goto L130;
    if (m == l-1){
      slaev2f(d[l-2], e[l-2], d[l-1], rt1, rt2, c, s);
      rot2(z, l-2, c, s);
      d[l-2] = rt1; d[l-1] = rt2; e[l-2] = 0.f;
      l -= 2;
      if (l >= lend) goto L90;
      goto L140;
    }
    if (jtot == nmaxit) goto L140;
    jtot++;
    g = (d[l-2] - p)/(2.f*e[l-2]);
    r = slapy2f(g, 1.f);
    g = d[m-1] - p + (e[l-2]/(g + copysignf(r, g)));
    s = 1.f; c = 1.f; p = 0.f;
    for (i = m; i <= l-1; ++i){
      f = s*e[i-1];
      b = c*e[i-1];
      slartgf(g, f, c, s, r);
      if (i != m) e[i-2] = r;
      g = d[i-1] - p;
      r = (d[i] - g)*s + 2.f*c*b;
      p = s*r;
      d[i-1] = g + p;
      g = c*r - b;
      cw[i-m] = c; sw[i-m] = s;
    }
    for (j = 1; j <= l-m; ++j) rot2(z, m+j-2, cw[j-1], sw[j-1]);
    d[l-1] = d[l-1] - p;
    e[l-2] = g;
    goto L90;
L130:
    d[l-1] = p;
    l -= 1;
    if (l >= lend) goto L90;
    goto L140;
  }
L140:
  if (iscale == 1){
    mul = anorm/ssfmax;
    for (i = lsv; i <= lendsv; ++i)   d[i-1] *= mul;
    for (i = lsv; i <= lendsv-1; ++i) e[i-1] *= mul;
  } else if (iscale == 2){
    mul = anorm/ssfmin;
    for (i = lsv; i <= lendsv; ++i)   d[i-1] *= mul;
    for (i = lsv; i <= lendsv-1; ++i) e[i-1] *= mul;
  }
  if (jtot < nmaxit) goto L10;
  return;
L160:
  for (ii = 2; ii <= n; ++ii){
    i = ii - 1; k = i; p = d[i-1];
    for (j = ii; j <= n; ++j){
      if (d[j-1] < p){ k = j; p = d[j-1]; }
    }
    if (k != i){
      d[k-1] = d[i-1]; d[i-1] = p;
      for (j = 0; j < 3; ++j){ float t = z[j][i-1]; z[j][i-1] = z[j][k-1]; z[j][k-1] = t; }
    }
  }
}

__device__ __noinline__ void eigh3_normal(float a11, float a21, float a31,
                                          float a22, float a32, float a33,
                                          float* out3){
#pragma clang fp contract(off)
  float d[3], e[2], z[3][3];
  float tau1 = 0.f, v2 = 0.f;
  float alpha = a21;
  float xnorm = fabsf(a31);
  if (xnorm == 0.f){
    e[0] = alpha;
    tau1 = 0.f;
  } else {
    float beta = -copysignf(slapy2f(alpha, xnorm), alpha);
    tau1 = (beta - alpha)/beta;
    v2 = a31*(1.f/(alpha - beta));
    float x1 = tau1*a22 + tau1*(a32*v2);
    float x2 = tau1*a32 + (tau1*v2)*a33;
    float al = -0.5f*tau1*(x1 + x2*v2);
    float w1 = x1 + al;
    float w2 = x2 + al*v2;
    a22 = a22 - w1 - w1;
    a32 = a32 - v2*w1 - w2;
    a33 = a33 - v2*w2 - w2*v2;
    e[0] = beta;
  }
  e[1] = a32;
  d[0] = a11; d[1] = a22; d[2] = a33;
  ssteqr3(d, e, z);
  if (tau1 != 0.f){
    #pragma unroll
    for (int jj = 0; jj < 3; ++jj){
      float wj  = z[1][jj] + v2*z[2][jj];
      float tmp = tau1*wj;
      z[1][jj] = z[1][jj] - tmp;
      z[2][jj] = z[2][jj] - v2*tmp;
    }
  }
  out3[0] = z[0][0]; out3[1] = z[1][0]; out3[2] = z[2][0];
}

// ---------------- distance helpers ----------------

__device__ __forceinline__ float sq3f(float x, float y, float z){
#pragma clang fp contract(off)
  return x*x + y*y + z*z;
}

__device__ __forceinline__ float d2f(float qs, float qx, float qy, float qz, float4 c){
#pragma clang fp contract(off)
  float dot = qx*c.x + qy*c.y + qz*c.z;
  return (qs + c.w) - 2.f*dot;
}

// ---------------- kernels ----------------

// grid 1024 x 256. Block: 64 queries of one (cloud,batch); 4 threads/query
// (wave h scans tile slice [h*512,(h+1)*512)). Per-thread sorted top-16 over
// its 2048 candidates, then exact 4-way lexicographic (d2,idx) merge ==
// lax.top_k selection (stable ties).
__global__ __launch_bounds__(256) void knn_normal_kernel(const float* __restrict__ pred,
                                                         const float* __restrict__ gt,
                                                         float* __restrict__ normals){
#pragma clang fp contract(off)
  __shared__ float4 tile[TS];                 // 32 KiB; reused as merge buffer
  const int bid   = blockIdx.x;
  const int cloud = bid >> 9;
  const int wi    = bid & 511;
  const int b     = wi >> 7;
  const int seg   = wi & 127;
  const float* __restrict__ base = (cloud ? gt : pred) + (size_t)b*(NPTS*3);
  const int lane = threadIdx.x & 63;
  const int h    = threadIdx.x >> 6;
  const int qi   = seg*64 + lane;
  const float qx = base[qi*3+0];
  const float qy = base[qi*3+1];
  const float qz = base[qi*3+2];
  const float qs = sq3f(qx, qy, qz);

  float bd[16]; int bidx[16];
  #pragma unroll
  for (int j = 0; j < 16; ++j){ bd[j] = 3.0e38f; bidx[j] = 0x7fffffff; }

  const int jb = h*512;
  for (int t0 = 0; t0 < NPTS; t0 += TS){
    __syncthreads();
    for (int t = threadIdx.x; t < TS; t += 256){
      const float* p = base + (size_t)(t0+t)*3;
      float x = p[0], y = p[1], z = p[2];
      tile[t] = make_float4(x, y, z, sq3f(x, y, z));
    }
    __syncthreads();
    #pragma unroll 4
    for (int j = 0; j < 512; ++j){
      float4 cpt = tile[jb + j];               // wave-uniform broadcast read
      float dd = d2f(qs, qx, qy, qz, cpt);
      if (dd < bd[15]){                        // strict <: lower idx wins ties
        bd[15] = dd; bidx[15] = t0 + jb + j;
        #pragma unroll
        for (int k = 15; k > 0; --k){
          if (bd[k] < bd[k-1]){
            float td = bd[k]; bd[k] = bd[k-1]; bd[k-1] = td;
            int ti = bidx[k]; bidx[k] = bidx[k-1]; bidx[k-1] = ti;
          }
        }
      }
    }
  }

  // ---- exact 4-way lex merge via LDS (entry-major: mbuf[r*256+tid], 2-way=free) ----
  __syncthreads();
  float2* mbuf = (float2*)tile;
  #pragma unroll
  for (int r = 0; r < 16; ++r)
    mbuf[r*256 + threadIdx.x] = make_float2(bd[r], __int_as_float(bidx[r]));
  __syncthreads();

  if (h == 0){
    int p0 = 0, p1 = 0, p2 = 0, p3 = 0;
    int nidx[16];
    #pragma unroll
    for (int r = 0; r < 16; ++r){
      float bestd; int besti; int bl;
      float dl; int il; bool better;
      // list 0 head (sentinel +inf when exhausted)
      if (p0 < 16){ float2 e = mbuf[p0*256 + lane]; bestd = e.x; besti = __float_as_int(e.y); }
      else { bestd = 3.4e38f; besti = 0x7fffffff; }
      bl = 0;
      if (p1 < 16){ float2 e = mbuf[p1*256 + 64 + lane]; dl = e.x; il = __float_as_int(e.y); }
      else { dl = 3.4e38f; il = 0x7fffffff; }
      better = (dl < bestd) || (dl == bestd && il < besti);
      if (better){ bestd = dl; besti = il; bl = 1; }
      if (p2 < 16){ float2 e = mbuf[p2*256 + 128 + lane]; dl = e.x; il = __float_as_int(e.y); }
      else { dl = 3.4e38f; il = 0x7fffffff; }
      better = (dl < bestd) || (dl == bestd && il < besti);
      if (better){ bestd = dl; besti = il; bl = 2; }
      if (p3 < 16){ float2 e = mbuf[p3*256 + 192 + lane]; dl = e.x; il = __float_as_int(e.y); }
      else { dl = 3.4e38f; il = 0x7fffffff; }
      better = (dl < bestd) || (dl == bestd && il < besti);
      if (better){ bestd = dl; besti = il; bl = 3; }
      nidx[r] = besti;
      p0 += (bl == 0); p1 += (bl == 1); p2 += (bl == 2); p3 += (bl == 3);
    }

    // gather neighbors in merged (top_k) order
    float gxx[16], gyy[16], gzz[16];
    #pragma unroll
    for (int r = 0; r < 16; ++r){
      const float* p = base + (size_t)nidx[r]*3;
      gxx[r] = p[0]; gyy[r] = p[1]; gzz[r] = p[2];
    }
    float mx = 0.f, my = 0.f, mz = 0.f;
    #pragma unroll
    for (int r = 0; r < 16; ++r){ mx += gxx[r]; my += gyy[r]; mz += gzz[r]; }
    mx *= 0.0625f; my *= 0.0625f; mz *= 0.0625f;

    float c00=0.f, c10=0.f, c20=0.f, c11=0.f, c21=0.f, c22=0.f;
    #pragma unroll
    for (int r = 0; r < 16; ++r){
      float cx = gxx[r]-mx, cy = gyy[r]-my, cz = gzz[r]-mz;
      c00 += cx*cx; c10 += cy*cx; c20 += cz*cx;
      c11 += cy*cy; c21 += cz*cy; c22 += cz*cz;
    }
    c00 *= 0.0625f; c10 *= 0.0625f; c20 *= 0.0625f;
    c11 *= 0.0625f; c21 *= 0.0625f; c22 *= 0.0625f;

    float nrm[3];
    eigh3_normal(c00, c10, c20, c11, c21, c22, nrm);

    float* o = normals + ((size_t)(cloud*NB + b)*NPTS + qi)*3;
    o[0] = nrm[0]; o[1] = nrm[1]; o[2] = nrm[2];
  }
}

__global__ __launch_bounds__(1024) void loss_kernel(const float* __restrict__ normals,
                                                    float* __restrict__ out){
  __shared__ float red[1024];
  const float4* a4 = (const float4*)normals;                        // 24576 float4
  const float4* g4 = (const float4*)(normals + (size_t)NB*NPTS*3);
  float acc = 0.f;
  for (int i = threadIdx.x; i < 24576; i += 1024){
    float4 a = a4[i], g = g4[i];
    acc += a.x*g.x + a.y*g.y + a.z*g.z + a.w*g.w;   // flat dot == sum of row dots
  }
  red[threadIdx.x] = acc;
  __syncthreads();
  for (int sft = 512; sft > 0; sft >>= 1){
    if (threadIdx.x < sft) red[threadIdx.x] += red[threadIdx.x + sft];
    __syncthreads();
  }
  if (threadIdx.x == 0) out[0] = 1.f - red[0]*(1.f/32768.f);
}

extern "C" void kernel_launch(void* const* d_in, const int* in_sizes, int n_in,
                              void* d_out, int out_size, void* d_ws, size_t ws_size,
                              hipStream_t stream) {
  const float* pred = (const float*)d_in[0];
  const float* gt   = (const float*)d_in[1];
  float* normals = (float*)d_ws;      // 2 * 4 * 8192 * 3 floats = 786 KiB
  knn_normal_kernel<<<1024, 256, 0, stream>>>(pred, gt, normals);
  loss_kernel<<<1, 1024, 0, stream>>>(normals, (float*)d_out);
}

// Round 4
// 648.404 us; speedup vs baseline: 1.8700x; 1.4474x over previous
//
#include <hip/hip_runtime.h>
#include <math.h>

// NormalConsistencyLoss: B=4, N=8192, D=3, K=16, fp32 in/out (scalar out).
// [knn_normal_kernel] exact 16-NN (4-way split scan + lazy buffered insert +
// exact lex merge) + PCA normal via faithful LAPACK ssyevd(fp32) port -> ws;
// [loss_kernel] 1-mean(dot).

#define NPTS 8192
#define NB   4
#define TS   2048

// ---------------- LAPACK single-precision ports (sign-faithful) ----------------

__device__ __forceinline__ float slapy2f(float x, float y){
#pragma clang fp contract(off)
  float xa = fabsf(x), ya = fabsf(y);
  float w = fmaxf(xa, ya), z = fminf(xa, ya);
  if (z == 0.f) return w;
  float t = z / w;
  return w * sqrtf(1.f + t*t);
}

// LAPACK >= 3.10 slartg (new convention: c >= 0 always, r = sign(d,f))
__device__ __forceinline__ void slartgf(float f, float g, float& c, float& s, float& r){
#pragma clang fp contract(off)
  const float safmin = 1.17549435e-38f;
  const float safmax = 8.50705917e37f;
  const float rtmin  = 1.08420217e-19f;
  const float rtmax  = 6.52318604e18f;
  if (g == 0.f){ c = 1.f; s = 0.f; r = f; }
  else if (f == 0.f){ c = 0.f; s = copysignf(1.f, g); r = fabsf(g); }
  else {
    float f1 = fabsf(f), g1 = fabsf(g);
    if (f1 > rtmin && f1 < rtmax && g1 > rtmin && g1 < rtmax){
      float d = sqrtf(f*f + g*g);
      c = f1 / d;
      r = copysignf(d, f);
      s = g / r;
    } else {
      float u = fminf(safmax, fmaxf(safmin, fmaxf(f1, g1)));
      float fs = f/u, gs = g/u;
      float d = sqrtf(fs*fs + gs*gs);
      c = fabsf(fs)/d;
      r = copysignf(d, f);
      r = r*u;
      s = g/r;
    }
  }
}

__device__ __forceinline__ void slaev2f(float a, float b, float cc,
                                        float& rt1, float& rt2, float& cs1, float& sn1){
#pragma clang fp contract(off)
  float sm  = a + cc;
  float df  = a - cc;
  float adf = fabsf(df);
  float tb  = b + b;
  float ab  = fabsf(tb);
  float acmx, acmn;
  if (fabsf(a) > fabsf(cc)){ acmx = a; acmn = cc; } else { acmx = cc; acmn = a; }
  float rt;
  if (adf > ab){ float t = ab/adf; rt = adf*sqrtf(1.f + t*t); }
  else if (adf < ab){ float t = adf/ab; rt = ab*sqrtf(1.f + t*t); }
  else rt = ab*sqrtf(2.f);
  int sgn1;
  if (sm < 0.f){ rt1 = 0.5f*(sm - rt); sgn1 = -1; rt2 = (acmx/rt1)*acmn - (b/rt1)*b; }
  else if (sm > 0.f){ rt1 = 0.5f*(sm + rt); sgn1 = 1; rt2 = (acmx/rt1)*acmn - (b/rt1)*b; }
  else { rt1 = 0.5f*rt; rt2 = -0.5f*rt; sgn1 = 1; }
  int sgn2; float cs;
  if (df >= 0.f){ cs = df + rt; sgn2 = 1; } else { cs = df - rt; sgn2 = -1; }
  float acs = fabsf(cs);
  if (acs > ab){ float ct = -tb/cs; sn1 = 1.f/sqrtf(1.f + ct*ct); cs1 = ct*sn1; }
  else {
    if (ab == 0.f){ cs1 = 1.f; sn1 = 0.f; }
    else { float tn = -cs/tb; cs1 = 1.f/sqrtf(1.f + tn*tn); sn1 = tn*cs1; }
  }
  if (sgn1 == sgn2){ float tn = cs1; cs1 = -sn1; sn1 = tn; }
}

__device__ __forceinline__ void rot2(float z[3][3], int ja, float c, float s){
#pragma clang fp contract(off)
  #pragma unroll
  for (int i = 0; i < 3; ++i){
    float t1 = z[i][ja+1];
    float t0 = z[i][ja];
    z[i][ja+1] = c*t1 - s*t0;
    z[i][ja]   = s*t1 + c*t0;
  }
}

// Faithful port of LAPACK ssteqr('I', n=3, d, e, z)
__device__ __noinline__ void ssteqr3(float* d, float* e, float z[3][3]){
#pragma clang fp contract(off)
  const float eps    = 5.96046448e-08f;
  const float eps2   = 3.55271368e-15f;
  const float safmin = 1.17549435e-38f;
  const float ssfmax = 3.07445735e+18f;
  const float ssfmin = 3.05175781e-05f;
  const int n = 3;
  float cw[2], sw[2];
  int nmaxit, jtot, l1, l, lsv, lend, lendsv, m, iscale, i, j, ii, k;
  float anorm, p, g, r, c, s, f, b, rt1, rt2, tst, mul;

  for (i = 0; i < 3; ++i) for (j = 0; j < 3; ++j) z[i][j] = (i == j) ? 1.f : 0.f;
  nmaxit = n*30; jtot = 0; l1 = 1; m = 0; iscale = 0; anorm = 0.f;
  lsv = 1; lendsv = 1; lend = 1; l = 1;

L10:
  if (l1 > n) goto L160;
  if (l1 > 1) e[l1-2] = 0.f;
  if (l1 <= n-1){
    for (m = l1; m <= n-1; ++m){
      tst = fabsf(e[m-1]);
      if (tst == 0.f) goto L30;
      if (tst <= (sqrtf(fabsf(d[m-1]))*sqrtf(fabsf(d[m])))*eps){ e[m-1] = 0.f; goto L30; }
    }
  }
  m = n;
L30:
  l = l1; lsv = l; lend = m; lendsv = lend; l1 = m + 1;
  if (lend == l) goto L10;
  anorm = 0.f;
  for (i = l; i <= lend; ++i)   anorm = fmaxf(anorm, fabsf(d[i-1]));
  for (i = l; i <= lend-1; ++i) anorm = fmaxf(anorm, fabsf(e[i-1]));
  iscale = 0;
  if (anorm == 0.f) goto L10;
  if (anorm > ssfmax){
    iscale = 1; mul = ssfmax/anorm;
    for (i = l; i <= lend; ++i)   d[i-1] *= mul;
    for (i = l; i <= lend-1; ++i) e[i-1] *= mul;
  } else if (anorm < ssfmin){
    iscale = 2; mul = ssfmin/anorm;
    for (i = l; i <= lend; ++i)   d[i-1] *= mul;
    for (i = l; i <= lend-1; ++i) e[i-1] *= mul;
  }
  if (fabsf(d[lend-1]) < fabsf(d[l-1])){ lend = lsv; l = lendsv; }

  if (lend > l){
L40:
    if (l != lend){
      for (m = l; m <= lend-1; ++m){
        tst = fabsf(e[m-1]); tst = tst*tst;
        if (tst <= (eps2*fabsf(d[m-1]))*fabsf(d[m]) + safmin) goto L60;
      }
    }
    m = lend;
L60:
    if (m < lend) e[m-1] = 0.f;
    p = d[l-1];
    if (m == l) goto L80;
    if (m == l+1){
      slaev2f(d[l-1], e[l-1], d[l], rt1, rt2, c, s);
      rot2(z, l-1, c, s);
      d[l-1] = rt1; d[l] = rt2; e[l-1] = 0.f;
      l += 2;
      if (l <= lend) goto L40;
      goto L140;
    }
    if (jtot == nmaxit) goto L140;
    jtot++;
    g = (d[l] - p)/(2.f*e[l-1]);
    r = slapy2f(g, 1.f);
    g = d[m-1] - p + (e[l-1]/(g + copysignf(r, g)));
    s = 1.f; c = 1.f; p = 0.f;
    for (i = m-1; i >= l; --i){
      f = s*e[i-1];
      b = c*e[i-1];
      slartgf(g, f, c, s, r);
      if (i != m-1) e[i] = r;
      g = d[i] - p;
      r = (d[i-1] - g)*s + 2.f*c*b;
      p = s*r;
      d[i] = g + p;
      g = c*r - b;
      cw[i-l] = c; sw[i-l] = -s;
    }
    for (j = m-l; j >= 1; --j) rot2(z, l+j-2, cw[j-1], sw[j-1]);
    d[l-1] = d[l-1] - p;
    e[l-1] = g;
    goto L40;
L80:
    d[l-1] = p;
    l += 1;
    if (l <= lend) goto L40;
    goto L140;
  } else {
L90:
    if (l != lend){
      for (m = l; m >= lend+1; --m){
        tst = fabsf(e[m-2]); tst = tst*tst;
        if (tst <= (eps2*fabsf(d[m-1]))*fabsf(d[m-2]) + safmin) goto L110;
      }
    }
    m = lend;
L110:
    if (m > lend) e[m-2] = 0.f;
    p = d[l-1];
    if (m == l) goto L130;
    if (m == l-1){
      slaev2f(d[l-2], e[l-2], d[l-1], rt1, rt2, c, s);
      rot2(z, l-2, c, s);
      d[l-2] = rt1; d[l-1] = rt2; e[l-2] = 0.f;
      l -= 2;
      if (l >= lend) goto L90;
      goto L140;
    }
    if (jtot == nmaxit) goto L140;
    jtot++;
    g = (d[l-2] - p)/(2.f*e[l-2]);
    r = slapy2f(g, 1.f);
    g = d[m-1] - p + (e[l-2]/(g + copysignf(r, g)));
    s = 1.f; c = 1.f; p = 0.f;
    for (i = m; i <= l-1; ++i){
      f = s*e[i-1];
      b = c*e[i-1];
      slartgf(g, f, c, s, r);
      if (i != m) e[i-2] = r;
      g = d[i-1] - p;
      r = (d[i] - g)*s + 2.f*c*b;
      p = s*r;
      d[i-1] = g + p;
      g = c*r - b;
      cw[i-m] = c; sw[i-m] = s;
    }
    for (j = 1; j <= l-m; ++j) rot2(z, m+j-2, cw[j-1], sw[j-1]);
    d[l-1] = d[l-1] - p;
    e[l-2] = g;
    goto L90;
L130:
    d[l-1] = p;
    l -= 1;
    if (l >= lend) goto L90;
    goto L140;
  }
L140:
  if (iscale == 1){
    mul = anorm/ssfmax;
    for (i = lsv; i <= lendsv; ++i)   d[i-1] *= mul;
    for (i = lsv; i <= lendsv-1; ++i) e[i-1] *= mul;
  } else if (iscale == 2){
    mul = anorm/ssfmin;
    for (i = lsv; i <= lendsv; ++i)   d[i-1] *= mul;
    for (i = lsv; i <= lendsv-1; ++i) e[i-1] *= mul;
  }
  if (jtot < nmaxit) goto L10;
  return;
L160:
  for (ii = 2; ii <= n; ++ii){
    i = ii - 1; k = i; p = d[i-1];
    for (j = ii; j <= n; ++j){
      if (d[j-1] < p){ k = j; p = d[j-1]; }
    }
    if (k != i){
      d[k-1] = d[i-1]; d[i-1] = p;
      for (j = 0; j < 3; ++j){ float t = z[j][i-1]; z[j][i-1] = z[j][k-1]; z[j][k-1] = t; }
    }
  }
}

__device__ __noinline__ void eigh3_normal(float a11, float a21, float a31,
                                          float a22, float a32, float a33,
                                          float* out3){
#pragma clang fp contract(off)
  float d[3], e[2], z[3][3];
  float tau1 = 0.f, v2 = 0.f;
  float alpha = a21;
  float xnorm = fabsf(a31);
  if (xnorm == 0.f){
    e[0] = alpha;
    tau1 = 0.f;
  } else {
    float beta = -copysignf(slapy2f(alpha, xnorm), alpha);
    tau1 = (beta - alpha)/beta;
    v2 = a31*(1.f/(alpha - beta));
    float x1 = tau1*a22 + tau1*(a32*v2);
    float x2 = tau1*a32 + (tau1*v2)*a33;
    float al = -0.5f*tau1*(x1 + x2*v2);
    float w1 = x1 + al;
    float w2 = x2 + al*v2;
    a22 = a22 - w1 - w1;
    a32 = a32 - v2*w1 - w2;
    a33 = a33 - v2*w2 - w2*v2;
    e[0] = beta;
  }
  e[1] = a32;
  d[0] = a11; d[1] = a22; d[2] = a33;
  ssteqr3(d, e, z);
  if (tau1 != 0.f){
    #pragma unroll
    for (int jj = 0; jj < 3; ++jj){
      float wj  = z[1][jj] + v2*z[2][jj];
      float tmp = tau1*wj;
      z[1][jj] = z[1][jj] - tmp;
      z[2][jj] = z[2][jj] - v2*tmp;
    }
  }
  out3[0] = z[0][0]; out3[1] = z[1][0]; out3[2] = z[2][0];
}

// ---------------- distance helpers ----------------

__device__ __forceinline__ float sq3f(float x, float y, float z){
#pragma clang fp contract(off)
  return x*x + y*y + z*z;
}

__device__ __forceinline__ float d2f(float qs, float qx, float qy, float qz, float4 c){
#pragma clang fp contract(off)
  float dot = qx*c.x + qy*c.y + qz*c.z;
  return (qs + c.w) - 2.f*dot;
}

// Sorted-insert into ascending 16-list; strict < everywhere => stable
// (equal keys keep arrival order = ascending candidate index).
__device__ __forceinline__ void insert16(float dd, int idx, float bd[16], int bidx[16]){
#pragma clang fp contract(off)
  if (dd < bd[15]){
    bd[15] = dd; bidx[15] = idx;
    #pragma unroll
    for (int k = 15; k > 0; --k){
      if (bd[k] < bd[k-1]){
        float td = bd[k]; bd[k] = bd[k-1]; bd[k-1] = td;
        int ti = bidx[k]; bidx[k] = bidx[k-1]; bidx[k-1] = ti;
      }
    }
  }
}

// ---------------- kernels ----------------

// grid 1024 x 256. Block: 64 queries of one (cloud,batch); 4 threads/query
// (wave h scans tile slice [h*512,(h+1)*512)). Per-thread sorted top-16 over
// its 2048 candidates with LAZY BUFFERED insert (depth-2 per-lane register
// buffer, stale threshold, wave-wide flush only when some lane is full) —
// final state provably identical to direct insertion. Then exact 4-way
// lexicographic (d2,idx) merge == lax.top_k selection.
__global__ __launch_bounds__(256) void knn_normal_kernel(const float* __restrict__ pred,
                                                         const float* __restrict__ gt,
                                                         float* __restrict__ normals){
#pragma clang fp contract(off)
  __shared__ float4 tile[TS];                 // 32 KiB; reused as merge buffer
  const int bid   = blockIdx.x;
  const int cloud = bid >> 9;
  const int wi    = bid & 511;
  const int b     = wi >> 7;
  const int seg   = wi & 127;
  const float* __restrict__ base = (cloud ? gt : pred) + (size_t)b*(NPTS*3);
  const int lane = threadIdx.x & 63;
  const int h    = threadIdx.x >> 6;
  const int qi   = seg*64 + lane;
  const float qx = base[qi*3+0];
  const float qy = base[qi*3+1];
  const float qz = base[qi*3+2];
  const float qs = sq3f(qx, qy, qz);

  float bd[16]; int bidx[16];
  #pragma unroll
  for (int j = 0; j < 16; ++j){ bd[j] = 3.0e38f; bidx[j] = 0x7fffffff; }

  // lazy-insert state: stale threshold + depth-2 per-lane buffer
  float thr = 3.0e38f;
  float c0d = 0.f, c1d = 0.f;
  int   c0i = 0,   c1i = 0,   cnt = 0;

  const int jb = h*512;
  for (int t0 = 0; t0 < NPTS; t0 += TS){
    __syncthreads();
    for (int t = threadIdx.x; t < TS; t += 256){
      const float* p = base + (size_t)(t0+t)*3;
      float x = p[0], y = p[1], z = p[2];
      tile[t] = make_float4(x, y, z, sq3f(x, y, z));
    }
    __syncthreads();
    #pragma unroll 2
    for (int j = 0; j < 512; ++j){
      float4 cpt = tile[jb + j];               // wave-uniform broadcast read
      float dd = d2f(qs, qx, qy, qz, cpt);     // exact reference-order value
      bool pass = dd < thr;                    // stale thr => superset, safe
      int idx = t0 + jb + j;
      bool w0 = pass && (cnt == 0);
      bool w1 = pass && (cnt == 1);
      c0d = w0 ? dd : c0d;  c0i = w0 ? idx : c0i;
      c1d = w1 ? dd : c1d;  c1i = w1 ? idx : c1i;
      cnt += (int)pass;
      if (__any(cnt == 2)){                    // flush: rare wave-wide event
        if (cnt >= 1) insert16(c0d, c0i, bd, bidx);
        if (cnt == 2) insert16(c1d, c1i, bd, bidx);
        cnt = 0;
        thr = bd[15];
      }
    }
  }
  // drain leftovers
  if (cnt >= 1) insert16(c0d, c0i, bd, bidx);
  if (cnt == 2) insert16(c1d, c1i, bd, bidx);

  // ---- exact 4-way lex merge via LDS (entry-major: mbuf[r*256+tid], 2-way=free) ----
  __syncthreads();
  float2* mbuf = (float2*)tile;
  #pragma unroll
  for (int r = 0; r < 16; ++r)
    mbuf[r*256 + threadIdx.x] = make_float2(bd[r], __int_as_float(bidx[r]));
  __syncthreads();

  if (h == 0){
    int p0 = 0, p1 = 0, p2 = 0, p3 = 0;
    int nidx[16];
    #pragma unroll
    for (int r = 0; r < 16; ++r){
      float bestd; int besti; int bl;
      float dl; int il; bool better;
      if (p0 < 16){ float2 e = mbuf[p0*256 + lane]; bestd = e.x; besti = __float_as_int(e.y); }
      else { bestd = 3.4e38f; besti = 0x7fffffff; }
      bl = 0;
      if (p1 < 16){ float2 e = mbuf[p1*256 + 64 + lane]; dl = e.x; il = __float_as_int(e.y); }
      else { dl = 3.4e38f; il = 0x7fffffff; }
      better = (dl < bestd) || (dl == bestd && il < besti);
      if (better){ bestd = dl; besti = il; bl = 1; }
      if (p2 < 16){ float2 e = mbuf[p2*256 + 128 + lane]; dl = e.x; il = __float_as_int(e.y); }
      else { dl = 3.4e38f; il = 0x7fffffff; }
      better = (dl < bestd) || (dl == bestd && il < besti);
      if (better){ bestd = dl; besti = il; bl = 2; }
      if (p3 < 16){ float2 e = mbuf[p3*256 + 192 + lane]; dl = e.x; il = __float_as_int(e.y); }
      else { dl = 3.4e38f; il = 0x7fffffff; }
      better = (dl < bestd) || (dl == bestd && il < besti);
      if (better){ bestd = dl; besti = il; bl = 3; }
      nidx[r] = besti;
      p0 += (bl == 0); p1 += (bl == 1); p2 += (bl == 2); p3 += (bl == 3);
    }

    // gather neighbors in merged (top_k) order
    float gxx[16], gyy[16], gzz[16];
    #pragma unroll
    for (int r = 0; r < 16; ++r){
      const float* p = base + (size_t)nidx[r]*3;
      gxx[r] = p[0]; gyy[r] = p[1]; gzz[r] = p[2];
    }
    float mx = 0.f, my = 0.f, mz = 0.f;
    #pragma unroll
    for (int r = 0; r < 16; ++r){ mx += gxx[r]; my += gyy[r]; mz += gzz[r]; }
    mx *= 0.0625f; my *= 0.0625f; mz *= 0.0625f;

    float c00=0.f, c10=0.f, c20=0.f, c11=0.f, c21=0.f, c22=0.f;
    #pragma unroll
    for (int r = 0; r < 16; ++r){
      float cx = gxx[r]-mx, cy = gyy[r]-my, cz = gzz[r]-mz;
      c00 += cx*cx; c10 += cy*cx; c20 += cz*cx;
      c11 += cy*cy; c21 += cz*cy; c22 += cz*cz;
    }
    c00 *= 0.0625f; c10 *= 0.0625f; c20 *= 0.0625f;
    c11 *= 0.0625f; c21 *= 0.0625f; c22 *= 0.0625f;

    float nrm[3];
    eigh3_normal(c00, c10, c20, c11, c21, c22, nrm);

    float* o = normals + ((size_t)(cloud*NB + b)*NPTS + qi)*3;
    o[0] = nrm[0]; o[1] = nrm[1]; o[2] = nrm[2];
  }
}

__global__ __launch_bounds__(1024) void loss_kernel(const float* __restrict__ normals,
                                                    float* __restrict__ out){
  __shared__ float red[1024];
  const float4* a4 = (const float4*)normals;                        // 24576 float4
  const float4* g4 = (const float4*)(normals + (size_t)NB*NPTS*3);
  float acc = 0.f;
  for (int i = threadIdx.x; i < 24576; i += 1024){
    float4 a = a4[i], g = g4[i];
    acc += a.x*g.x + a.y*g.y + a.z*g.z + a.w*g.w;   // flat dot == sum of row dots
  }
  red[threadIdx.x] = acc;
  __syncthreads();
  for (int sft = 512; sft > 0; sft >>= 1){
    if (threadIdx.x < sft) red[threadIdx.x] += red[threadIdx.x + sft];
    __syncthreads();
  }
  if (threadIdx.x == 0) out[0] = 1.f - red[0]*(1.f/32768.f);
}

extern "C" void kernel_launch(void* const* d_in, const int* in_sizes, int n_in,
                              void* d_out, int out_size, void* d_ws, size_t ws_size,
                              hipStream_t stream) {
  const float* pred = (const float*)d_in[0];
  const float* gt   = (const float*)d_in[1];
  float* normals = (float*)d_ws;      // 2 * 4 * 8192 * 3 floats = 786 KiB
  knn_normal_kernel<<<1024, 256, 0, stream>>>(pred, gt, normals);
  loss_kernel<<<1, 1024, 0, stream>>>(normals, (float*)d_out);
}

// Round 5
// 621.149 us; speedup vs baseline: 1.9520x; 1.0439x over previous
//
#include <hip/hip_runtime.h>
#include <math.h>

// NormalConsistencyLoss: B=4, N=8192, D=3, K=16, fp32 in/out (scalar out).
// [knn_normal_kernel] exact 16-NN (4-way split scan + depth-4 lazy buffer +
// exact lex merge) + PCA normal via faithful LAPACK ssyevd(fp32) port -> ws;
// [loss_partial/loss_final] 1-mean(dot).

#define NPTS 8192
#define NB   4
#define TS   2048

// ---------------- LAPACK single-precision ports (sign-faithful) ----------------

__device__ __forceinline__ float slapy2f(float x, float y){
#pragma clang fp contract(off)
  float xa = fabsf(x), ya = fabsf(y);
  float w = fmaxf(xa, ya), z = fminf(xa, ya);
  if (z == 0.f) return w;
  float t = z / w;
  return w * sqrtf(1.f + t*t);
}

// LAPACK >= 3.10 slartg (new convention: c >= 0 always, r = sign(d,f))
__device__ __forceinline__ void slartgf(float f, float g, float& c, float& s, float& r){
#pragma clang fp contract(off)
  const float safmin = 1.17549435e-38f;
  const float safmax = 8.50705917e37f;
  const float rtmin  = 1.08420217e-19f;
  const float rtmax  = 6.52318604e18f;
  if (g == 0.f){ c = 1.f; s = 0.f; r = f; }
  else if (f == 0.f){ c = 0.f; s = copysignf(1.f, g); r = fabsf(g); }
  else {
    float f1 = fabsf(f), g1 = fabsf(g);
    if (f1 > rtmin && f1 < rtmax && g1 > rtmin && g1 < rtmax){
      float d = sqrtf(f*f + g*g);
      c = f1 / d;
      r = copysignf(d, f);
      s = g / r;
    } else {
      float u = fminf(safmax, fmaxf(safmin, fmaxf(f1, g1)));
      float fs = f/u, gs = g/u;
      float d = sqrtf(fs*fs + gs*gs);
      c = fabsf(fs)/d;
      r = copysignf(d, f);
      r = r*u;
      s = g/r;
    }
  }
}

__device__ __forceinline__ void slaev2f(float a, float b, float cc,
                                        float& rt1, float& rt2, float& cs1, float& sn1){
#pragma clang fp contract(off)
  float sm  = a + cc;
  float df  = a - cc;
  float adf = fabsf(df);
  float tb  = b + b;
  float ab  = fabsf(tb);
  float acmx, acmn;
  if (fabsf(a) > fabsf(cc)){ acmx = a; acmn = cc; } else { acmx = cc; acmn = a; }
  float rt;
  if (adf > ab){ float t = ab/adf; rt = adf*sqrtf(1.f + t*t); }
  else if (adf < ab){ float t = adf/ab; rt = ab*sqrtf(1.f + t*t); }
  else rt = ab*sqrtf(2.f);
  int sgn1;
  if (sm < 0.f){ rt1 = 0.5f*(sm - rt); sgn1 = -1; rt2 = (acmx/rt1)*acmn - (b/rt1)*b; }
  else if (sm > 0.f){ rt1 = 0.5f*(sm + rt); sgn1 = 1; rt2 = (acmx/rt1)*acmn - (b/rt1)*b; }
  else { rt1 = 0.5f*rt; rt2 = -0.5f*rt; sgn1 = 1; }
  int sgn2; float cs;
  if (df >= 0.f){ cs = df + rt; sgn2 = 1; } else { cs = df - rt; sgn2 = -1; }
  float acs = fabsf(cs);
  if (acs > ab){ float ct = -tb/cs; sn1 = 1.f/sqrtf(1.f + ct*ct); cs1 = ct*sn1; }
  else {
    if (ab == 0.f){ cs1 = 1.f; sn1 = 0.f; }
    else { float tn = -cs/tb; cs1 = 1.f/sqrtf(1.f + tn*tn); sn1 = tn*cs1; }
  }
  if (sgn1 == sgn2){ float tn = cs1; cs1 = -sn1; sn1 = tn; }
}

__device__ __forceinline__ void rot2(float z[3][3], int ja, float c, float s){
#pragma clang fp contract(off)
  #pragma unroll
  for (int i = 0; i < 3; ++i){
    float t1 = z[i][ja+1];
    float t0 = z[i][ja];
    z[i][ja+1] = c*t1 - s*t0;
    z[i][ja]   = s*t1 + c*t0;
  }
}

// Faithful port of LAPACK ssteqr('I', n=3, d, e, z)
__device__ __noinline__ void ssteqr3(float* d, float* e, float z[3][3]){
#pragma clang fp contract(off)
  const float eps    = 5.96046448e-08f;
  const float eps2   = 3.55271368e-15f;
  const float safmin = 1.17549435e-38f;
  const float ssfmax = 3.07445735e+18f;
  const float ssfmin = 3.05175781e-05f;
  const int n = 3;
  float cw[2], sw[2];
  int nmaxit, jtot, l1, l, lsv, lend, lendsv, m, iscale, i, j, ii, k;
  float anorm, p, g, r, c, s, f, b, rt1, rt2, tst, mul;

  for (i = 0; i < 3; ++i) for (j = 0; j < 3; ++j) z[i][j] = (i == j) ? 1.f : 0.f;
  nmaxit = n*30; jtot = 0; l1 = 1; m = 0; iscale = 0; anorm = 0.f;
  lsv = 1; lendsv = 1; lend = 1; l = 1;

L10:
  if (l1 > n) goto L160;
  if (l1 > 1) e[l1-2] = 0.f;
  if (l1 <= n-1){
    for (m = l1; m <= n-1; ++m){
      tst = fabsf(e[m-1]);
      if (tst == 0.f) goto L30;
      if (tst <= (sqrtf(fabsf(d[m-1]))*sqrtf(fabsf(d[m])))*eps){ e[m-1] = 0.f; goto L30; }
    }
  }
  m = n;
L30:
  l = l1; lsv = l; lend = m; lendsv = lend; l1 = m + 1;
  if (lend == l) goto L10;
  anorm = 0.f;
  for (i = l; i <= lend; ++i)   anorm = fmaxf(anorm, fabsf(d[i-1]));
  for (i = l; i <= lend-1; ++i) anorm = fmaxf(anorm, fabsf(e[i-1]));
  iscale = 0;
  if (anorm == 0.f) goto L10;
  if (anorm > ssfmax){
    iscale = 1; mul = ssfmax/anorm;
    for (i = l; i <= lend; ++i)   d[i-1] *= mul;
    for (i = l; i <= lend-1; ++i) e[i-1] *= mul;
  } else if (anorm < ssfmin){
    iscale = 2; mul = ssfmin/anorm;
    for (i = l; i <= lend; ++i)   d[i-1] *= mul;
    for (i = l; i <= lend-1; ++i) e[i-1] *= mul;
  }
  if (fabsf(d[lend-1]) < fabsf(d[l-1])){ lend = lsv; l = lendsv; }

  if (lend > l){
L40:
    if (l != lend){
      for (m = l; m <= lend-1; ++m){
        tst = fabsf(e[m-1]); tst = tst*tst;
        if (tst <= (eps2*fabsf(d[m-1]))*fabsf(d[m]) + safmin) goto L60;
      }
    }
    m = lend;
L60:
    if (m < lend) e[m-1] = 0.f;
    p = d[l-1];
    if (m == l) goto L80;
    if (m == l+1){
      slaev2f(d[l-1], e[l-1], d[l], rt1, rt2, c, s);
      rot2(z, l-1, c, s);
      d[l-1] = rt1; d[l] = rt2; e[l-1] = 0.f;
      l += 2;
      if (l <= lend) goto L40;
      goto L140;
    }
    if (jtot == nmaxit) goto L140;
    jtot++;
    g = (d[l] - p)/(2.f*e[l-1]);
    r = slapy2f(g, 1.f);
    g = d[m-1] - p + (e[l-1]/(g + copysignf(r, g)));
    s = 1.f; c = 1.f; p = 0.f;
    for (i = m-1; i >= l; --i){
      f = s*e[i-1];
      b = c*e[i-1];
      slartgf(g, f, c, s, r);
      if (i != m-1) e[i] = r;
      g = d[i] - p;
      r = (d[i-1] - g)*s + 2.f*c*b;
      p = s*r;
      d[i] = g + p;
      g = c*r - b;
      cw[i-l] = c; sw[i-l] = -s;
    }
    for (j = m-l; j >= 1; --j) rot2(z, l+j-2, cw[j-1], sw[j-1]);
    d[l-1] = d[l-1] - p;
    e[l-1] = g;
    goto L40;
L80:
    d[l-1] = p;
    l += 1;
    if (l <= lend) goto L40;
    goto L140;
  } else {
L90:
    if (l != lend){
      for (m = l; m >= lend+1; --m){
        tst = fabsf(e[m-2]); tst = tst*tst;
        if (tst <= (eps2*fabsf(d[m-1]))*fabsf(d[m-2]) + safmin) goto L110;
      }
    }
    m = lend;
L110:
    if (m > lend) e[m-2] = 0.f;
    p = d[l-1];
    if (m == l) goto L130;
    if (m == l-1){
      slaev2f(d[l-2], e[l-2], d[l-1], rt1, rt2, c, s);
      rot2(z, l-2, c, s);
      d[l-2] = rt1; d[l-1] = rt2; e[l-2] = 0.f;
      l -= 2;
      if (l >= lend) goto L90;
      goto L140;
    }
    if (jtot == nmaxit) goto L140;
    jtot++;
    g = (d[l-2] - p)/(2.f*e[l-2]);
    r = slapy2f(g, 1.f);
    g = d[m-1] - p + (e[l-2]/(g + copysignf(r, g)));
    s = 1.f; c = 1.f; p = 0.f;
    for (i = m; i <= l-1; ++i){
      f = s*e[i-1];
      b = c*e[i-1];
      slartgf(g, f, c, s, r);
      if (i != m) e[i-2] = r;
      g = d[i-1] - p;
      r = (d[i] - g)*s + 2.f*c*b;
      p = s*r;
      d[i-1] = g + p;
      g = c*r - b;
      cw[i-m] = c; sw[i-m] = s;
    }
    for (j = 1; j <= l-m; ++j) rot2(z, m+j-2, cw[j-1], sw[j-1]);
    d[l-1] = d[l-1] - p;
    e[l-2] = g;
    goto L90;
L130:
    d[l-1] = p;
    l -= 1;
    if (l >= lend) goto L90;
    goto L140;
  }
L140:
  if (iscale == 1){
    mul = anorm/ssfmax;
    for (i = lsv; i <= lendsv; ++i)   d[i-1] *= mul;
    for (i = lsv; i <= lendsv-1; ++i) e[i-1] *= mul;
  } else if (iscale == 2){
    mul = anorm/ssfmin;
    for (i = lsv; i <= lendsv; ++i)   d[i-1] *= mul;
    for (i = lsv; i <= lendsv-1; ++i) e[i-1] *= mul;
  }
  if (jtot < nmaxit) goto L10;
  return;
L160:
  for (ii = 2; ii <= n; ++ii){
    i = ii - 1; k = i; p = d[i-1];
    for (j = ii; j <= n; ++j){
      if (d[j-1] < p){ k = j; p = d[j-1]; }
    }
    if (k != i){
      d[k-1] = d[i-1]; d[i-1] = p;
      for (j = 0; j < 3; ++j){ float t = z[j][i-1]; z[j][i-1] = z[j][k-1]; z[j][k-1] = t; }
    }
  }
}

__device__ __noinline__ void eigh3_normal(float a11, float a21, float a31,
                                          float a22, float a32, float a33,
                                          float* out3){
#pragma clang fp contract(off)
  float d[3], e[2], z[3][3];
  float tau1 = 0.f, v2 = 0.f;
  float alpha = a21;
  float xnorm = fabsf(a31);
  if (xnorm == 0.f){
    e[0] = alpha;
    tau1 = 0.f;
  } else {
    float beta = -copysignf(slapy2f(alpha, xnorm), alpha);
    tau1 = (beta - alpha)/beta;
    v2 = a31*(1.f/(alpha - beta));
    float x1 = tau1*a22 + tau1*(a32*v2);
    float x2 = tau1*a32 + (tau1*v2)*a33;
    float al = -0.5f*tau1*(x1 + x2*v2);
    float w1 = x1 + al;
    float w2 = x2 + al*v2;
    a22 = a22 - w1 - w1;
    a32 = a32 - v2*w1 - w2;
    a33 = a33 - v2*w2 - w2*v2;
    e[0] = beta;
  }
  e[1] = a32;
  d[0] = a11; d[1] = a22; d[2] = a33;
  ssteqr3(d, e, z);
  if (tau1 != 0.f){
    #pragma unroll
    for (int jj = 0; jj < 3; ++jj){
      float wj  = z[1][jj] + v2*z[2][jj];
      float tmp = tau1*wj;
      z[1][jj] = z[1][jj] - tmp;
      z[2][jj] = z[2][jj] - v2*tmp;
    }
  }
  out3[0] = z[0][0]; out3[1] = z[1][0]; out3[2] = z[2][0];
}

// ---------------- distance helpers ----------------

__device__ __forceinline__ float sq3f(float x, float y, float z){
#pragma clang fp contract(off)
  return x*x + y*y + z*z;
}

__device__ __forceinline__ float d2f(float qs, float qx, float qy, float qz, float4 c){
#pragma clang fp contract(off)
  float dot = qx*c.x + qy*c.y + qz*c.z;
  return (qs + c.w) - 2.f*dot;
}

// Sorted-insert into ascending 16-list; strict < everywhere => stable
// (equal keys keep arrival order = ascending candidate index).
__device__ __forceinline__ void insert16(float dd, int idx, float bd[16], int bidx[16]){
#pragma clang fp contract(off)
  if (dd < bd[15]){
    bd[15] = dd; bidx[15] = idx;
    #pragma unroll
    for (int k = 15; k > 0; --k){
      if (bd[k] < bd[k-1]){
        float td = bd[k]; bd[k] = bd[k-1]; bd[k-1] = td;
        int ti = bidx[k]; bidx[k] = bidx[k-1]; bidx[k-1] = ti;
      }
    }
  }
}

// ---------------- kernels ----------------

// grid 1024 x 256. Block: 64 queries of one (cloud,batch); 4 threads/query
// (wave h scans tile slice [h*512,(h+1)*512)). Depth-4 lazy shift-buffer:
// buffer update gated on __any(pass) (uniform branch); wave-wide flush only
// when some lane has 4 buffered. Drain oldest-first => per-thread list is
// bit-identical to direct insertion. Then exact 4-way lex merge == lax.top_k.
__global__ __launch_bounds__(256) void knn_normal_kernel(const float* __restrict__ pred,
                                                         const float* __restrict__ gt,
                                                         float* __restrict__ normals){
#pragma clang fp contract(off)
  __shared__ float4 tile[TS];                 // 32 KiB; reused as merge buffer
  const int bid   = blockIdx.x;
  const int cloud = bid >> 9;
  const int wi    = bid & 511;
  const int b     = wi >> 7;
  const int seg   = wi & 127;
  const float* __restrict__ base = (cloud ? gt : pred) + (size_t)b*(NPTS*3);
  const int lane = threadIdx.x & 63;
  const int h    = threadIdx.x >> 6;
  const int qi   = seg*64 + lane;
  const float qx = base[qi*3+0];
  const float qy = base[qi*3+1];
  const float qz = base[qi*3+2];
  const float qs = sq3f(qx, qy, qz);

  float bd[16]; int bidx[16];
  #pragma unroll
  for (int j = 0; j < 16; ++j){ bd[j] = 3.0e38f; bidx[j] = 0x7fffffff; }

  // depth-4 lazy shift buffer (c0 newest ... c3 oldest) + stale threshold
  float thr = 3.0e38f;
  float c0d = 0.f, c1d = 0.f, c2d = 0.f, c3d = 0.f;
  int   c0i = 0,   c1i = 0,   c2i = 0,   c3i = 0,   cnt = 0;

#define FLUSH_BUF() do {                                   \
    if (cnt > 3) insert16(c3d, c3i, bd, bidx);             \
    if (cnt > 2) insert16(c2d, c2i, bd, bidx);             \
    if (cnt > 1) insert16(c1d, c1i, bd, bidx);             \
    if (cnt > 0) insert16(c0d, c0i, bd, bidx);             \
    cnt = 0; thr = bd[15];                                 \
  } while (0)

  const int jb = h*512;
  for (int t0 = 0; t0 < NPTS; t0 += TS){
    __syncthreads();
    for (int t = threadIdx.x; t < TS; t += 256){
      const float* p = base + (size_t)(t0+t)*3;
      float x = p[0], y = p[1], z = p[2];
      tile[t] = make_float4(x, y, z, sq3f(x, y, z));
    }
    __syncthreads();
    #pragma unroll 4
    for (int j = 0; j < 512; ++j){
      float4 cpt = tile[jb + j];               // wave-uniform broadcast read
      float dd = d2f(qs, qx, qy, qz, cpt);     // exact reference-order value
      bool pass = dd < thr;                    // stale thr => superset, safe
      if (__any(pass)){                        // uniform branch, ~50-60% taken
        int idx = t0 + jb + j;
        c3d = pass ? c2d : c3d;  c3i = pass ? c2i : c3i;
        c2d = pass ? c1d : c2d;  c2i = pass ? c1i : c2i;
        c1d = pass ? c0d : c1d;  c1i = pass ? c0i : c1i;
        c0d = pass ? dd  : c0d;  c0i = pass ? idx : c0i;
        cnt += (int)pass;
        if (__any(cnt >= 4)) FLUSH_BUF();      // rare: ~90 flushes / 8192 iters
      }
    }
  }
  FLUSH_BUF();                                 // drain leftovers
#undef FLUSH_BUF

  // ---- exact 4-way lex merge via LDS (entry-major: mbuf[r*256+tid], 2-way=free) ----
  __syncthreads();
  float2* mbuf = (float2*)tile;
  #pragma unroll
  for (int r = 0; r < 16; ++r)
    mbuf[r*256 + threadIdx.x] = make_float2(bd[r], __int_as_float(bidx[r]));
  __syncthreads();

  if (h == 0){
    int p0 = 0, p1 = 0, p2 = 0, p3 = 0;
    int nidx[16];
    #pragma unroll
    for (int r = 0; r < 16; ++r){
      float bestd; int besti; int bl;
      float dl; int il; bool better;
      if (p0 < 16){ float2 e = mbuf[p0*256 + lane]; bestd = e.x; besti = __float_as_int(e.y); }
      else { bestd = 3.4e38f; besti = 0x7fffffff; }
      bl = 0;
      if (p1 < 16){ float2 e = mbuf[p1*256 + 64 + lane]; dl = e.x; il = __float_as_int(e.y); }
      else { dl = 3.4e38f; il = 0x7fffffff; }
      better = (dl < bestd) || (dl == bestd && il < besti);
      if (better){ bestd = dl; besti = il; bl = 1; }
      if (p2 < 16){ float2 e = mbuf[p2*256 + 128 + lane]; dl = e.x; il = __float_as_int(e.y); }
      else { dl = 3.4e38f; il = 0x7fffffff; }
      better = (dl < bestd) || (dl == bestd && il < besti);
      if (better){ bestd = dl; besti = il; bl = 2; }
      if (p3 < 16){ float2 e = mbuf[p3*256 + 192 + lane]; dl = e.x; il = __float_as_int(e.y); }
      else { dl = 3.4e38f; il = 0x7fffffff; }
      better = (dl < bestd) || (dl == bestd && il < besti);
      if (better){ bestd = dl; besti = il; bl = 3; }
      nidx[r] = besti;
      p0 += (bl == 0); p1 += (bl == 1); p2 += (bl == 2); p3 += (bl == 3);
    }

    // gather neighbors in merged (top_k) order
    float gxx[16], gyy[16], gzz[16];
    #pragma unroll
    for (int r = 0; r < 16; ++r){
      const float* p = base + (size_t)nidx[r]*3;
      gxx[r] = p[0]; gyy[r] = p[1]; gzz[r] = p[2];
    }
    float mx = 0.f, my = 0.f, mz = 0.f;
    #pragma unroll
    for (int r = 0; r < 16; ++r){ mx += gxx[r]; my += gyy[r]; mz += gzz[r]; }
    mx *= 0.0625f; my *= 0.0625f; mz *= 0.0625f;

    float c00=0.f, c10=0.f, c20=0.f, c11=0.f, c21=0.f, c22=0.f;
    #pragma unroll
    for (int r = 0; r < 16; ++r){
      float cx = gxx[r]-mx, cy = gyy[r]-my, cz = gzz[r]-mz;
      c00 += cx*cx; c10 += cy*cx; c20 += cz*cx;
      c11 += cy*cy; c21 += cz*cy; c22 += cz*cz;
    }
    c00 *= 0.0625f; c10 *= 0.0625f; c20 *= 0.0625f;
    c11 *= 0.0625f; c21 *= 0.0625f; c22 *= 0.0625f;

    float nrm[3];
    eigh3_normal(c00, c10, c20, c11, c21, c22, nrm);

    float* o = normals + ((size_t)(cloud*NB + b)*NPTS + qi)*3;
    o[0] = nrm[0]; o[1] = nrm[1]; o[2] = nrm[2];
  }
}

// 64 blocks x 256 thr: block partial sums of the flat dot.
__global__ __launch_bounds__(256) void loss_partial(const float* __restrict__ normals,
                                                    float* __restrict__ partials){
  __shared__ float red[256];
  const float4* a4 = (const float4*)normals;                        // 24576 float4
  const float4* g4 = (const float4*)(normals + (size_t)NB*NPTS*3);
  float acc = 0.f;
  for (int i = blockIdx.x*256 + threadIdx.x; i < 24576; i += 64*256){
    float4 a = a4[i], g = g4[i];
    acc += a.x*g.x + a.y*g.y + a.z*g.z + a.w*g.w;
  }
  red[threadIdx.x] = acc;
  __syncthreads();
  for (int sft = 128; sft > 0; sft >>= 1){
    if (threadIdx.x < sft) red[threadIdx.x] += red[threadIdx.x + sft];
    __syncthreads();
  }
  if (threadIdx.x == 0) partials[blockIdx.x] = red[0];
}

__global__ void loss_final(const float* __restrict__ partials,
                           float* __restrict__ out){
  float v = partials[threadIdx.x];             // 64 lanes, one partial each
  #pragma unroll
  for (int s = 32; s > 0; s >>= 1) v += __shfl_down(v, s, 64);
  if (threadIdx.x == 0) out[0] = 1.f - v*(1.f/32768.f);
}

extern "C" void kernel_launch(void* const* d_in, const int* in_sizes, int n_in,
                              void* d_out, int out_size, void* d_ws, size_t ws_size,
                              hipStream_t stream) {
  const float* pred = (const float*)d_in[0];
  const float* gt   = (const float*)d_in[1];
  float* normals  = (float*)d_ws;                       // 2*4*8192*3 floats = 786 KiB
  float* partials = normals + (size_t)2*NB*NPTS*3;      // +64 floats
  knn_normal_kernel<<<1024, 256, 0, stream>>>(pred, gt, normals);
  loss_partial<<<64, 256, 0, stream>>>(normals, partials);
  loss_final<<<1, 64, 0, stream>>>(partials, (float*)d_out);
}